// Round 10
// baseline (672.807 us; speedup 1.0000x reference)
//
#include <hip/hip_runtime.h>
#include <math.h>

#define HID 128
#define NSTEPS 64
#define SLEN 65
#define THREADS 256
#define ROWS 32       // R22: half tile, same 32 cols/wave -> 4 WGs/CU spill-free
#define ASTRIDE 136   // 128 + 8 f16 pad, 16B aligned rows
#define FSTRIDE 40    // 32 + 8 f16 pad
#define DSTR 68       // 64 + 4 f32 pad, 16B-aligned rows for b128 flush reads

typedef _Float16 half8 __attribute__((ext_vector_type(8)));
typedef __fp16 fp16x2 __attribute__((ext_vector_type(2)));
typedef float floatx4 __attribute__((ext_vector_type(4)));

// R22 = R21 4-phase structure at ROWS=32, grid 1024, launch_bounds(256,4):
// the occupancy experiment with BOTH prior failure modes jointly avoided.
//  - R15 spilled: wfrag was 128 VGPR vs the 128 cap. Now wfrag=96 and
//    R21 measured 120 TOTAL incl acc[4][2]=32 -> baseline ~88; acc[2][2]=8
//    here -> est peak ~96-105 <= 128. Spill gate: FETCH/WRITE must stay
//    ~6-14MB / 8.2MB.
//  - R16/R17 doubled LDS traffic: they cut cols/wave 32->16. Here cols/wave
//    stays 32 (traffic law: LDS bytes/output ~ 128/colsPerWave, unchanged);
//    per-wave A-tile halves with the tile (8KB/GEMM).
// Result: 4 WGs/CU = 16 waves/CU = 4 waves/SIMD (2x R21) at identical
// per-output LDS/MFMA/VALU totals. LDS 37.3KB/WG x4 = 149KB <= 160.
// Structure (R21): G2 deleted; v = lrelu(h0@sW1 + u@W25 + cvec), W25 =
// rW2@sW1 computed at init by 4 FULLY-UNROLLED GEMM passes (rule #20:
// wfrag[2][p] indices compile-time); d = sigmoid(h0.Wf + u.wfu + v.ws2f
// + C) via 3 broadcast-B MFMA chains (waves 0-1; 32 rows).
// 4 phases = algorithmic minimum (featb->h0->u->v->delta nonlinear chain).
// CLOSED: cols/wave != 32 (R3 spill; R16/R17 traffic law); XOR swizzle
// (R14 structural); acc live across barriers (R18 spill at the 128 cliff);
// runtime-indexed frag arrays (R20, rule #20); phase deletion beyond 4.
__global__ __launch_bounds__(THREADS, 4)
void hedger(const float* __restrict__ S,
            const float* __restrict__ W0,  const float* __restrict__ b0,
            const float* __restrict__ rW1, const float* __restrict__ rb1,
            const float* __restrict__ rW2, const float* __restrict__ rb2,
            const float* __restrict__ sW1, const float* __restrict__ sb1,
            const float* __restrict__ sW2, const float* __restrict__ sb2,
            const float* __restrict__ Wf,  const float* __restrict__ bfp,
            float* __restrict__ out)
{
  __shared__ __align__(16) _Float16 bufA[ROWS * ASTRIDE];   // h0    8704 B
  __shared__ __align__(16) _Float16 bufB[ROWS * ASTRIDE];   // u     8704 B
  __shared__ __align__(16) _Float16 bufC[ROWS * ASTRIDE];   // v     8704 B
  __shared__ __align__(16) _Float16 featb[ROWS * FSTRIDE];  //       2560 B
  __shared__ __align__(16) _Float16 WfS[HID];               //        256 B
  __shared__ __align__(16) _Float16 WfuS[HID];              // rW2@Wf 256 B
  __shared__ __align__(16) _Float16 Ws2S[HID];              // sW2@Wf 256 B
  __shared__             float    CvalS;
  __shared__ __align__(16) float    deltab[ROWS * DSTR];    //       8704 B
  // total ~38.1 KB -> 4 WGs/CU

  const int tid  = threadIdx.x;
  const int wave = tid >> 6;            // 0..3
  const int lane = tid & 63;
  const int l15  = lane & 15;
  const int quad = lane >> 4;
  const int n_base = wave * 32;
  const int r0 = blockIdx.x * ROWS;
  const int col0 = n_base + 2 * l15;    // lane's adjacent column pair

  // ---- persistent B fragments (96 VGPR): m=0 rW1, m=1 sW1, m=2 W25.
  half8 wfrag[3][4][2];  // [matrix][kIter][nt]
  {
    const float* Wm[2] = {rW1, sW1};
#pragma unroll
    for (int m = 0; m < 2; ++m)
#pragma unroll
      for (int kq = 0; kq < 4; ++kq)
#pragma unroll
        for (int nt = 0; nt < 2; ++nt) {
          const int n  = col0 + nt;
          const int kb = kq * 32 + quad * 8;
          half8 f;
#pragma unroll
          for (int j = 0; j < 8; ++j)
            f[j] = (_Float16)Wm[m][(kb + j) * HID + n];
          wfrag[m][kq][nt] = f;
        }
  }
  // W0 (8x128) zero-padded to K=32: only quad 0 (k<8) is real.
  half8 w0frag[2];
#pragma unroll
  for (int nt = 0; nt < 2; ++nt) {
    const int n = col0 + nt;
    half8 f;
#pragma unroll
    for (int j = 0; j < 8; ++j) {
      const int k = quad * 8 + j;
      f[j] = (k < 8) ? (_Float16)W0[k * HID + n] : (_Float16)0.f;
    }
    w0frag[nt] = f;
  }
  // biases: b0, rb1 direct; cvec = rb2@sW1 + sb1 via the lane's own sW1
  // fragments (quads partition k; shfl_xor 16/32 completes the dot).
  float b0r[2], rb1r[2], cv[2];
#pragma unroll
  for (int nt = 0; nt < 2; ++nt) {
    const int n = col0 + nt;
    b0r[nt] = b0[n]; rb1r[nt] = rb1[n];
    float p = 0.f;
#pragma unroll
    for (int kq = 0; kq < 4; ++kq) {
      const int kb = kq * 32 + quad * 8;
#pragma unroll
      for (int j = 0; j < 8; ++j)
        p += rb2[kb + j] * (float)wfrag[1][kq][nt][j];
    }
    p += __shfl_xor(p, 16);
    p += __shfl_xor(p, 32);
    cv[nt] = p + sb1[n];
  }

  // LDS init: featb zero-fill (pad cols 8..31 stay zero), Wf / wfu / ws2f
  // vectors, C scalar.
  for (int i = tid; i < ROWS * FSTRIDE; i += THREADS) featb[i] = (_Float16)0.f;
  if (tid < HID) {
    WfS[tid] = (_Float16)Wf[tid];
    float su = 0.f, ss = 0.f;
    for (int n = 0; n < HID; ++n) {
      su += rW2[tid * HID + n] * Wf[n];
      ss += sW2[tid * HID + n] * Wf[n];
    }
    WfuS[tid] = (_Float16)su;
    Ws2S[tid] = (_Float16)ss;
  }
  if (wave == 0) {   // C = (rb2 + sb2).Wf + bf
    float p = (rb2[lane] + sb2[lane]) * Wf[lane]
            + (rb2[lane + 64] + sb2[lane + 64]) * Wf[lane + 64];
    p += __shfl_xor(p, 1);  p += __shfl_xor(p, 2);  p += __shfl_xor(p, 4);
    p += __shfl_xor(p, 8);  p += __shfl_xor(p, 16); p += __shfl_xor(p, 32);
    if (lane == 0) CvalS = p + bfp[0];
  }

  floatx4 acc[2];   // [mt][nt] flattened as acc2 below; see macros

  // acc layout: accM[mt][nt] as 2x2 floatx4; declared as named array
  floatx4 acc00, acc01, acc10, acc11;
#define ACC(MT, NT) acc##MT##NT

#define INIT_BIAS(BR) do { \
  floatx4 z0 = {BR[0], BR[0], BR[0], BR[0]}; \
  floatx4 z1 = {BR[1], BR[1], BR[1], BR[1]}; \
  ACC(0,0) = z0; ACC(0,1) = z1; ACC(1,0) = z0; ACC(1,1) = z1; } while (0)

#define GEMM128(SRC, MI) do { \
  _Pragma("unroll") for (int kq = 0; kq < 4; ++kq) { \
    const half8 af0 = *(const half8*)&SRC[(l15) * ASTRIDE + kq * 32 + quad * 8]; \
    const half8 af1 = *(const half8*)&SRC[(16 + l15) * ASTRIDE + kq * 32 + quad * 8]; \
    ACC(0,0) = __builtin_amdgcn_mfma_f32_16x16x32_f16(af0, wfrag[MI][kq][0], ACC(0,0), 0, 0, 0); \
    ACC(0,1) = __builtin_amdgcn_mfma_f32_16x16x32_f16(af0, wfrag[MI][kq][1], ACC(0,1), 0, 0, 0); \
    ACC(1,0) = __builtin_amdgcn_mfma_f32_16x16x32_f16(af1, wfrag[MI][kq][0], ACC(1,0), 0, 0, 0); \
    ACC(1,1) = __builtin_amdgcn_mfma_f32_16x16x32_f16(af1, wfrag[MI][kq][1], ACC(1,1), 0, 0, 0); \
  } } while (0)

#define EPI_LRELU_MT(DST, MT) do { \
  _Pragma("unroll") for (int r = 0; r < 4; ++r) { \
    const int row = MT * 16 + quad * 4 + r; \
    const float v0 = ACC(MT,0)[r]; \
    const float v1 = ACC(MT,1)[r]; \
    fp16x2 h2 = {(__fp16)fmaxf(v0, 0.2f * v0), (__fp16)fmaxf(v1, 0.2f * v1)}; \
    *(fp16x2*)&DST[row * ASTRIDE + col0] = h2; \
  } } while (0)
#define EPI_LRELU(DST) do { EPI_LRELU_MT(DST, 0); EPI_LRELU_MT(DST, 1); } while (0)

#define EPI_STORE_MT(DST, MT) do { \
  _Pragma("unroll") for (int r = 0; r < 4; ++r) { \
    const int row = MT * 16 + quad * 4 + r; \
    fp16x2 h2 = {(__fp16)ACC(MT,0)[r], (__fp16)ACC(MT,1)[r]}; \
    *(fp16x2*)&DST[row * ASTRIDE + col0] = h2; \
  } } while (0)
#define EPI_STORE(DST) do { EPI_STORE_MT(DST, 0); EPI_STORE_MT(DST, 1); } while (0)

  // ---- init-time W25 = rW2 @ sW1 via the GEMM machinery: 4 FULLY-UNROLLED
  // passes (rule #20: wfrag[2][p] indices compile-time). Pass p stages rW2
  // rows [32p,32p+32) into bufA, GEMMs vs sW1 frags, EPI to bufB, gathers
  // W25 k-rows [32p,32p+32) = this pass's kq=p B-fragment.
#pragma unroll
  for (int p = 0; p < 4; ++p) {
    __syncthreads();                       // bufA/bufB free (covers featb fill)
    for (int i = tid; i < ROWS * HID; i += THREADS) {
      const int row = i >> 7, c = i & 127;
      bufA[row * ASTRIDE + c] = (_Float16)rW2[(p * 32 + row) * HID + c];
    }
    __syncthreads();
    {
      float zr[2] = {0.f, 0.f};
      INIT_BIAS(zr);
      GEMM128(bufA, 1);
      EPI_STORE(bufB);
    }
    __syncthreads();
    {
      half8 f0, f1;
#pragma unroll
      for (int j = 0; j < 8; ++j) {
        const int kl = quad * 8 + j;       // 0..31 within this pass
        const fp16x2 pr = *(const fp16x2*)&bufB[kl * ASTRIDE + col0];
        f0[j] = (_Float16)pr[0];
        f1[j] = (_Float16)pr[1];
      }
      wfrag[2][p][0] = f0;
      wfrag[2][p][1] = f1;
    }
  }
  __syncthreads();   // gathers done; bufA/bufB return to loop use

  // step-0 features (threads 0..31, one row each; S read from global)
  float lm_prev = 0.f, cum_x = 0.f, qv = 0.f;
  const float* Srow = S + (size_t)(r0 + (tid & (ROWS - 1))) * SLEN;
  if (tid < ROWS) {
    const float lm = logf(Srow[0] * 0.01f);
    lm_prev = lm; cum_x = lm; qv = 0.f;
    _Float16* fr = &featb[tid * FSTRIDE];
    fr[0] = (_Float16)lm;
    fr[1] = (_Float16)1.0f;
    fr[2] = (_Float16)0.235f;
    fr[3] = (_Float16)0.f;                 // delta_0 = 0
    fr[4] = (_Float16)lm;                  // run_mean at k=0
    fr[5] = (_Float16)0.f;
    fr[6] = (_Float16)(1.9f * sqrtf(1e-12f));
    fr[7] = (_Float16)0.f;
  }
  __syncthreads();
  const float Cval = CvalS;

#pragma unroll 1
  for (int k = 0; k < NSTEPS; ++k) {
    // G0: h0 = lrelu(featPad @ W0pad + b0)
    INIT_BIAS(b0r);
    {
      const half8 af0 = *(const half8*)&featb[(l15) * FSTRIDE + quad * 8];
      const half8 af1 = *(const half8*)&featb[(16 + l15) * FSTRIDE + quad * 8];
      ACC(0,0) = __builtin_amdgcn_mfma_f32_16x16x32_f16(af0, w0frag[0], ACC(0,0), 0, 0, 0);
      ACC(0,1) = __builtin_amdgcn_mfma_f32_16x16x32_f16(af0, w0frag[1], ACC(0,1), 0, 0, 0);
      ACC(1,0) = __builtin_amdgcn_mfma_f32_16x16x32_f16(af1, w0frag[0], ACC(1,0), 0, 0, 0);
      ACC(1,1) = __builtin_amdgcn_mfma_f32_16x16x32_f16(af1, w0frag[1], ACC(1,1), 0, 0, 0);
    }
    EPI_LRELU(bufA);
    __syncthreads();                                   // bar A: h0 in bufA

    // delta-independent features of step k+1 — overlaps G1.
    // (Srow[k+1] valid at k=63: SLEN=65; write is dead then, harmless.)
    if (tid < ROWS) {
      const int kk = k + 1;
      const float lm = logf(Srow[kk] * 0.01f);
      const float rr = lm - lm_prev; qv += rr * rr;
      lm_prev = lm; cum_x += lm;
      const float tT = (float)kk * (1.f / 64.f);
      _Float16* fr = &featb[tid * FSTRIDE];
      fr[0] = (_Float16)lm;
      fr[1] = (_Float16)(1.f - tT);
      fr[4] = (_Float16)(cum_x / (float)(kk + 1));
      fr[5] = (_Float16)qv;
      fr[6] = (_Float16)(1.9f * sqrtf(qv + 1e-12f));
      fr[7] = (_Float16)tT;
    }

    // G1: u = lrelu(h0 @ rW1 + rb1)
    INIT_BIAS(rb1r);  GEMM128(bufA, 0);  EPI_LRELU(bufB);
    __syncthreads();                                   // bar B: u in bufB

    // G23: v = lrelu(h0 @ sW1 + u @ W25 + cvec)   (G2 deleted)
    INIT_BIAS(cv);
    GEMM128(bufA, 1);
    GEMM128(bufB, 2);
    EPI_LRELU(bufC);
    __syncthreads();                                   // bar C: v in bufC

    // WF: delta = sigmoid(h0.Wf + u.wfu + v.ws2f + C); waves 0,1 cover the
    // 32 rows via three independent broadcast-B MFMA chains.
    if (wave < 2) {
      floatx4 d1 = {0.f, 0.f, 0.f, 0.f};
      floatx4 d2 = {0.f, 0.f, 0.f, 0.f};
      floatx4 d3 = {0.f, 0.f, 0.f, 0.f};
      const int arow = (wave * 16 + l15) * ASTRIDE;
#pragma unroll
      for (int kq = 0; kq < 4; ++kq) {
        const int off = kq * 32 + quad * 8;
        const half8 a1 = *(const half8*)&bufA[arow + off];
        const half8 w1 = *(const half8*)&WfS[off];
        d1 = __builtin_amdgcn_mfma_f32_16x16x32_f16(a1, w1, d1, 0, 0, 0);
        const half8 a2 = *(const half8*)&bufB[arow + off];
        const half8 w2 = *(const half8*)&WfuS[off];
        d2 = __builtin_amdgcn_mfma_f32_16x16x32_f16(a2, w2, d2, 0, 0, 0);
        const half8 a3 = *(const half8*)&bufC[arow + off];
        const half8 w3 = *(const half8*)&Ws2S[off];
        d3 = __builtin_amdgcn_mfma_f32_16x16x32_f16(a3, w3, d3, 0, 0, 0);
      }
      if (l15 < 4) {
        // static-index select (rule: no runtime vector index)
        const float s1 = (l15 & 2) ? ((l15 & 1) ? d1[3] : d1[2])
                                   : ((l15 & 1) ? d1[1] : d1[0]);
        const float s2 = (l15 & 2) ? ((l15 & 1) ? d2[3] : d2[2])
                                   : ((l15 & 1) ? d2[1] : d2[0]);
        const float s3 = (l15 & 2) ? ((l15 & 1) ? d3[3] : d3[2])
                                   : ((l15 & 1) ? d3[1] : d3[0]);
        const int row = wave * 16 + quad * 4 + l15;
        const float d = 1.f / (1.f + expf(-(s1 + s2 + s3 + Cval)));
        featb[row * FSTRIDE + 3] = (_Float16)d;        // fr[3] for step k+1
        deltab[row * DSTR + k] = d;                    // staged output
      }
    }
    __syncthreads();                                   // bar D: featb complete
  }

  // coalesced output flush: 32 rows x 64 steps, dwordx4 stores.
  {
    const int row = tid >> 3;                // 0..31
    const int c0  = (tid & 7) * 8;           // 0,8,...,56
    const float* dr = &deltab[row * DSTR + c0];
    float* orow = &out[(size_t)(r0 + row) * NSTEPS + c0];
#pragma unroll
    for (int u = 0; u < 2; ++u) {
      const floatx4 v = *(const floatx4*)&dr[u * 4];
      *(floatx4*)&orow[u * 4] = v;
    }
  }
#undef INIT_BIAS
#undef GEMM128
#undef EPI_LRELU
#undef EPI_LRELU_MT
#undef EPI_STORE
#undef EPI_STORE_MT
#undef ACC
}

extern "C" void kernel_launch(void* const* d_in, const int* in_sizes, int n_in,
                              void* d_out, int out_size, void* d_ws, size_t ws_size,
                              hipStream_t stream) {
  const float* S   = (const float*)d_in[0];
  const float* W0  = (const float*)d_in[1];
  const float* b0  = (const float*)d_in[2];
  const float* rW1 = (const float*)d_in[3];
  const float* rb1 = (const float*)d_in[4];
  const float* rW2 = (const float*)d_in[5];
  const float* rb2 = (const float*)d_in[6];
  const float* sW1 = (const float*)d_in[7];
  const float* sb1 = (const float*)d_in[8];
  const float* sW2 = (const float*)d_in[9];
  const float* sb2 = (const float*)d_in[10];
  const float* Wf  = (const float*)d_in[11];
  const float* bf  = (const float*)d_in[12];
  float* out = (float*)d_out;

  const int B = out_size / NSTEPS;        // 32768
  const int nblocks = B / ROWS;           // 1024 WGs -> 4 per CU
  hedger<<<nblocks, THREADS, 0, stream>>>(
      S, W0, b0, rW1, rb1, rW2, rb2, sW1, sb1, sW2, sb2, Wf, bf, out);
}

// Round 11
// 400.547 us; speedup vs baseline: 1.6797x; 1.6797x over previous
//
#include <hip/hip_runtime.h>
#include <math.h>

#define HID 128
#define NSTEPS 64
#define SLEN 65
#define THREADS 256
#define ROWS 32       // R23: grid 1024 -> 4 WGs/CU via NATURAL residency
#define ASTRIDE 136   // 128 + 8 f16 pad, 16B aligned rows
#define FSTRIDE 40    // 32 + 8 f16 pad
#define DSTR 68       // 64 + 4 f32 pad, 16B-aligned rows for b128 flush reads

typedef _Float16 half8 __attribute__((ext_vector_type(8)));
typedef __fp16 fp16x2 __attribute__((ext_vector_type(2)));
typedef float floatx4 __attribute__((ext_vector_type(4)));

// R23 = R21 4-phase structure, ROWS=32, grid=1024, launch_bounds(256,2).
// R22 LAW: __launch_bounds__ min-waves>2 collapses the allocator's arch-
// VGPR target to 64 (seen in R15 AND R22: VGPR_Count=64, weights->scratch,
// FETCH ~2-3GB). The bound was never needed: R21's natural 120 VGPR <= 128
// means HW already allows 4 waves/SIMD; R21 was GRID-limited (512 WGs =
// 2 WG/CU). Fix: keep bound (,2) so the compiler allocates exactly as the
// spill-free R21 did, and raise residency via grid=1024. Margin under the
// 128 boundary: acc 32->16 (half tile) and w0frag -> LDS W0B (R16-proven,
// -8 VGPR) => est ~100-115. LDS 40.4KB x4 = 161.8 <= 163.8KB.
// Gates: VGPR_Count <= 128 (else occupancy stays 2WG/CU -> null result);
// WRITE ~= 8.2MB out / FETCH ~6MB (else spill -> revert to R21).
// Structure (R21): G2 deleted; v = lrelu(h0@sW1 + u@W25 + cvec), W25 =
// rW2@sW1 at init via 4 FULLY-UNROLLED GEMM passes (rule #20); d =
// sigmoid(h0.Wf + u.wfu + v.ws2f + C) via 3 broadcast-B chains (waves 0-1).
// CLOSED: cols/wave != 32 (R3; R16/R17 traffic law 128/colsPerWave);
// min-waves>2 bounds (R15/R22 allocator law); XOR swizzle (R14); acc live
// across barriers (R18); runtime-indexed frag arrays (R20); <4 phases.
__global__ __launch_bounds__(THREADS, 2)
void hedger(const float* __restrict__ S,
            const float* __restrict__ W0,  const float* __restrict__ b0,
            const float* __restrict__ rW1, const float* __restrict__ rb1,
            const float* __restrict__ rW2, const float* __restrict__ rb2,
            const float* __restrict__ sW1, const float* __restrict__ sb1,
            const float* __restrict__ sW2, const float* __restrict__ sb2,
            const float* __restrict__ Wf,  const float* __restrict__ bfp,
            float* __restrict__ out)
{
  __shared__ __align__(16) _Float16 bufA[ROWS * ASTRIDE];   // h0    8704 B
  __shared__ __align__(16) _Float16 bufB[ROWS * ASTRIDE];   // u     8704 B
  __shared__ __align__(16) _Float16 bufC[ROWS * ASTRIDE];   // v     8704 B
  __shared__ __align__(16) _Float16 featb[ROWS * FSTRIDE];  //       2560 B
  __shared__ __align__(16) _Float16 WfS[HID];               //        256 B
  __shared__ __align__(16) _Float16 WfuS[HID];              // rW2@Wf 256 B
  __shared__ __align__(16) _Float16 Ws2S[HID];              // sW2@Wf 256 B
  __shared__ __align__(16) _Float16 W0B[HID * 8];           //       2048 B  [col][j]=W0[j][col]
  __shared__             float    CvalS;
  __shared__ __align__(16) float    deltab[ROWS * DSTR];    //       8704 B
  // total ~40.4 KB -> 4 WGs/CU (161.8 <= 163.8 KB)

  const int tid  = threadIdx.x;
  const int wave = tid >> 6;            // 0..3
  const int lane = tid & 63;
  const int l15  = lane & 15;
  const int quad = lane >> 4;
  const int n_base = wave * 32;
  const int r0 = blockIdx.x * ROWS;
  const int col0 = n_base + 2 * l15;    // lane's adjacent column pair

  // ---- persistent B fragments (96 VGPR): m=0 rW1, m=1 sW1, m=2 W25.
  half8 wfrag[3][4][2];  // [matrix][kIter][nt]
  {
    const float* Wm[2] = {rW1, sW1};
#pragma unroll
    for (int m = 0; m < 2; ++m)
#pragma unroll
      for (int kq = 0; kq < 4; ++kq)
#pragma unroll
        for (int nt = 0; nt < 2; ++nt) {
          const int n  = col0 + nt;
          const int kb = kq * 32 + quad * 8;
          half8 f;
#pragma unroll
          for (int j = 0; j < 8; ++j)
            f[j] = (_Float16)Wm[m][(kb + j) * HID + n];
          wfrag[m][kq][nt] = f;
        }
  }
  // biases: b0, rb1 direct; cvec = rb2@sW1 + sb1 via the lane's own sW1
  // fragments (quads partition k; shfl_xor 16/32 completes the dot).
  float b0r[2], rb1r[2], cv[2];
#pragma unroll
  for (int nt = 0; nt < 2; ++nt) {
    const int n = col0 + nt;
    b0r[nt] = b0[n]; rb1r[nt] = rb1[n];
    float p = 0.f;
#pragma unroll
    for (int kq = 0; kq < 4; ++kq) {
      const int kb = kq * 32 + quad * 8;
#pragma unroll
      for (int j = 0; j < 8; ++j)
        p += rb2[kb + j] * (float)wfrag[1][kq][nt][j];
    }
    p += __shfl_xor(p, 16);
    p += __shfl_xor(p, 32);
    cv[nt] = p + sb1[n];
  }

  // LDS init: featb zero-fill (pad cols 8..31 stay zero), Wf / wfu / ws2f,
  // W0B (B-frag transpose: W0B[c*8+j] = W0[j][c]), C scalar.
  for (int i = tid; i < ROWS * FSTRIDE; i += THREADS) featb[i] = (_Float16)0.f;
  if (tid < HID) {
    WfS[tid] = (_Float16)Wf[tid];
    float su = 0.f, ss = 0.f;
    for (int n = 0; n < HID; ++n) {
      su += rW2[tid * HID + n] * Wf[n];
      ss += sW2[tid * HID + n] * Wf[n];
    }
    WfuS[tid] = (_Float16)su;
    Ws2S[tid] = (_Float16)ss;
#pragma unroll
    for (int j = 0; j < 8; ++j) W0B[tid * 8 + j] = (_Float16)W0[j * HID + tid];
  }
  if (wave == 0) {   // C = (rb2 + sb2).Wf + bf
    float p = (rb2[lane] + sb2[lane]) * Wf[lane]
            + (rb2[lane + 64] + sb2[lane + 64]) * Wf[lane + 64];
    p += __shfl_xor(p, 1);  p += __shfl_xor(p, 2);  p += __shfl_xor(p, 4);
    p += __shfl_xor(p, 8);  p += __shfl_xor(p, 16); p += __shfl_xor(p, 32);
    if (lane == 0) CvalS = p + bfp[0];
  }

  // acc: 2x2 named floatx4 (16 VGPR), static indexing throughout
  floatx4 acc00, acc01, acc10, acc11;
#define ACC(MT, NT) acc##MT##NT

#define INIT_BIAS(BR) do { \
  floatx4 z0 = {BR[0], BR[0], BR[0], BR[0]}; \
  floatx4 z1 = {BR[1], BR[1], BR[1], BR[1]}; \
  ACC(0,0) = z0; ACC(0,1) = z1; ACC(1,0) = z0; ACC(1,1) = z1; } while (0)

#define GEMM128(SRC, MI) do { \
  _Pragma("unroll") for (int kq = 0; kq < 4; ++kq) { \
    const half8 af0 = *(const half8*)&SRC[(l15) * ASTRIDE + kq * 32 + quad * 8]; \
    const half8 af1 = *(const half8*)&SRC[(16 + l15) * ASTRIDE + kq * 32 + quad * 8]; \
    ACC(0,0) = __builtin_amdgcn_mfma_f32_16x16x32_f16(af0, wfrag[MI][kq][0], ACC(0,0), 0, 0, 0); \
    ACC(0,1) = __builtin_amdgcn_mfma_f32_16x16x32_f16(af0, wfrag[MI][kq][1], ACC(0,1), 0, 0, 0); \
    ACC(1,0) = __builtin_amdgcn_mfma_f32_16x16x32_f16(af1, wfrag[MI][kq][0], ACC(1,0), 0, 0, 0); \
    ACC(1,1) = __builtin_amdgcn_mfma_f32_16x16x32_f16(af1, wfrag[MI][kq][1], ACC(1,1), 0, 0, 0); \
  } } while (0)

#define EPI_LRELU_MT(DST, MT) do { \
  _Pragma("unroll") for (int r = 0; r < 4; ++r) { \
    const int row = MT * 16 + quad * 4 + r; \
    const float v0 = ACC(MT,0)[r]; \
    const float v1 = ACC(MT,1)[r]; \
    fp16x2 h2 = {(__fp16)fmaxf(v0, 0.2f * v0), (__fp16)fmaxf(v1, 0.2f * v1)}; \
    *(fp16x2*)&DST[row * ASTRIDE + col0] = h2; \
  } } while (0)
#define EPI_LRELU(DST) do { EPI_LRELU_MT(DST, 0); EPI_LRELU_MT(DST, 1); } while (0)

#define EPI_STORE_MT(DST, MT) do { \
  _Pragma("unroll") for (int r = 0; r < 4; ++r) { \
    const int row = MT * 16 + quad * 4 + r; \
    fp16x2 h2 = {(__fp16)ACC(MT,0)[r], (__fp16)ACC(MT,1)[r]}; \
    *(fp16x2*)&DST[row * ASTRIDE + col0] = h2; \
  } } while (0)
#define EPI_STORE(DST) do { EPI_STORE_MT(DST, 0); EPI_STORE_MT(DST, 1); } while (0)

  // ---- init-time W25 = rW2 @ sW1: 4 FULLY-UNROLLED GEMM passes (rule #20:
  // wfrag[2][p] indices compile-time). Pass p stages rW2 rows [32p,32p+32)
  // into bufA, GEMMs vs sW1 frags, EPI to bufB, gathers kq=p B-fragment.
#pragma unroll
  for (int p = 0; p < 4; ++p) {
    __syncthreads();                       // bufA/bufB free (covers featb fill)
    for (int i = tid; i < ROWS * HID; i += THREADS) {
      const int row = i >> 7, c = i & 127;
      bufA[row * ASTRIDE + c] = (_Float16)rW2[(p * 32 + row) * HID + c];
    }
    __syncthreads();
    {
      float zr[2] = {0.f, 0.f};
      INIT_BIAS(zr);
      GEMM128(bufA, 1);
      EPI_STORE(bufB);
    }
    __syncthreads();
    {
      half8 f0, f1;
#pragma unroll
      for (int j = 0; j < 8; ++j) {
        const int kl = quad * 8 + j;       // 0..31 within this pass
        const fp16x2 pr = *(const fp16x2*)&bufB[kl * ASTRIDE + col0];
        f0[j] = (_Float16)pr[0];
        f1[j] = (_Float16)pr[1];
      }
      wfrag[2][p][0] = f0;
      wfrag[2][p][1] = f1;
    }
  }
  __syncthreads();   // gathers done; bufA/bufB return to loop use

  // step-0 features (threads 0..31, one row each; S read from global)
  float lm_prev = 0.f, cum_x = 0.f, qv = 0.f;
  const float* Srow = S + (size_t)(r0 + (tid & (ROWS - 1))) * SLEN;
  if (tid < ROWS) {
    const float lm = logf(Srow[0] * 0.01f);
    lm_prev = lm; cum_x = lm; qv = 0.f;
    _Float16* fr = &featb[tid * FSTRIDE];
    fr[0] = (_Float16)lm;
    fr[1] = (_Float16)1.0f;
    fr[2] = (_Float16)0.235f;
    fr[3] = (_Float16)0.f;                 // delta_0 = 0
    fr[4] = (_Float16)lm;                  // run_mean at k=0
    fr[5] = (_Float16)0.f;
    fr[6] = (_Float16)(1.9f * sqrtf(1e-12f));
    fr[7] = (_Float16)0.f;
  }
  __syncthreads();
  const float Cval = CvalS;

#pragma unroll 1
  for (int k = 0; k < NSTEPS; ++k) {
    // G0: h0 = lrelu(featPad @ W0pad + b0); W0 B-frag from LDS (quad 0
    // real, quads 1..3 supply the K-pad zeros).
    INIT_BIAS(b0r);
    {
      half8 w0f0, w0f1;
      if (quad == 0) {
        w0f0 = *(const half8*)&W0B[(col0)     * 8];
        w0f1 = *(const half8*)&W0B[(col0 + 1) * 8];
      } else {
        half8 z = {0,0,0,0,0,0,0,0};
        w0f0 = z; w0f1 = z;
      }
      const half8 af0 = *(const half8*)&featb[(l15) * FSTRIDE + quad * 8];
      const half8 af1 = *(const half8*)&featb[(16 + l15) * FSTRIDE + quad * 8];
      ACC(0,0) = __builtin_amdgcn_mfma_f32_16x16x32_f16(af0, w0f0, ACC(0,0), 0, 0, 0);
      ACC(0,1) = __builtin_amdgcn_mfma_f32_16x16x32_f16(af0, w0f1, ACC(0,1), 0, 0, 0);
      ACC(1,0) = __builtin_amdgcn_mfma_f32_16x16x32_f16(af1, w0f0, ACC(1,0), 0, 0, 0);
      ACC(1,1) = __builtin_amdgcn_mfma_f32_16x16x32_f16(af1, w0f1, ACC(1,1), 0, 0, 0);
    }
    EPI_LRELU(bufA);
    __syncthreads();                                   // bar A: h0 in bufA

    // delta-independent features of step k+1 — overlaps G1.
    // (Srow[k+1] valid at k=63: SLEN=65; write is dead then, harmless.)
    if (tid < ROWS) {
      const int kk = k + 1;
      const float lm = logf(Srow[kk] * 0.01f);
      const float rr = lm - lm_prev; qv += rr * rr;
      lm_prev = lm; cum_x += lm;
      const float tT = (float)kk * (1.f / 64.f);
      _Float16* fr = &featb[tid * FSTRIDE];
      fr[0] = (_Float16)lm;
      fr[1] = (_Float16)(1.f - tT);
      fr[4] = (_Float16)(cum_x / (float)(kk + 1));
      fr[5] = (_Float16)qv;
      fr[6] = (_Float16)(1.9f * sqrtf(qv + 1e-12f));
      fr[7] = (_Float16)tT;
    }

    // G1: u = lrelu(h0 @ rW1 + rb1)
    INIT_BIAS(rb1r);  GEMM128(bufA, 0);  EPI_LRELU(bufB);
    __syncthreads();                                   // bar B: u in bufB

    // G23: v = lrelu(h0 @ sW1 + u @ W25 + cvec)   (G2 deleted)
    INIT_BIAS(cv);
    GEMM128(bufA, 1);
    GEMM128(bufB, 2);
    EPI_LRELU(bufC);
    __syncthreads();                                   // bar C: v in bufC

    // WF: delta = sigmoid(h0.Wf + u.wfu + v.ws2f + C); waves 0,1 cover the
    // 32 rows via three independent broadcast-B MFMA chains.
    if (wave < 2) {
      floatx4 d1 = {0.f, 0.f, 0.f, 0.f};
      floatx4 d2 = {0.f, 0.f, 0.f, 0.f};
      floatx4 d3 = {0.f, 0.f, 0.f, 0.f};
      const int arow = (wave * 16 + l15) * ASTRIDE;
#pragma unroll
      for (int kq = 0; kq < 4; ++kq) {
        const int off = kq * 32 + quad * 8;
        const half8 a1 = *(const half8*)&bufA[arow + off];
        const half8 w1 = *(const half8*)&WfS[off];
        d1 = __builtin_amdgcn_mfma_f32_16x16x32_f16(a1, w1, d1, 0, 0, 0);
        const half8 a2 = *(const half8*)&bufB[arow + off];
        const half8 w2 = *(const half8*)&WfuS[off];
        d2 = __builtin_amdgcn_mfma_f32_16x16x32_f16(a2, w2, d2, 0, 0, 0);
        const half8 a3 = *(const half8*)&bufC[arow + off];
        const half8 w3 = *(const half8*)&Ws2S[off];
        d3 = __builtin_amdgcn_mfma_f32_16x16x32_f16(a3, w3, d3, 0, 0, 0);
      }
      if (l15 < 4) {
        // static-index select (rule: no runtime vector index)
        const float s1 = (l15 & 2) ? ((l15 & 1) ? d1[3] : d1[2])
                                   : ((l15 & 1) ? d1[1] : d1[0]);
        const float s2 = (l15 & 2) ? ((l15 & 1) ? d2[3] : d2[2])
                                   : ((l15 & 1) ? d2[1] : d2[0]);
        const float s3 = (l15 & 2) ? ((l15 & 1) ? d3[3] : d3[2])
                                   : ((l15 & 1) ? d3[1] : d3[0]);
        const int row = wave * 16 + quad * 4 + l15;
        const float d = 1.f / (1.f + expf(-(s1 + s2 + s3 + Cval)));
        featb[row * FSTRIDE + 3] = (_Float16)d;        // fr[3] for step k+1
        deltab[row * DSTR + k] = d;                    // staged output
      }
    }
    __syncthreads();                                   // bar D: featb complete
  }

  // coalesced output flush: 32 rows x 64 steps, dwordx4 stores.
  {
    const int row = tid >> 3;                // 0..31
    const int c0  = (tid & 7) * 8;           // 0,8,...,56
    const float* dr = &deltab[row * DSTR + c0];
    float* orow = &out[(size_t)(r0 + row) * NSTEPS + c0];
#pragma unroll
    for (int u = 0; u < 2; ++u) {
      const floatx4 v = *(const floatx4*)&dr[u * 4];
      *(floatx4*)&orow[u * 4] = v;
    }
  }
#undef INIT_BIAS
#undef GEMM128
#undef EPI_LRELU
#undef EPI_LRELU_MT
#undef EPI_STORE
#undef EPI_STORE_MT
#undef ACC
}

extern "C" void kernel_launch(void* const* d_in, const int* in_sizes, int n_in,
                              void* d_out, int out_size, void* d_ws, size_t ws_size,
                              hipStream_t stream) {
  const float* S   = (const float*)d_in[0];
  const float* W0  = (const float*)d_in[1];
  const float* b0  = (const float*)d_in[2];
  const float* rW1 = (const float*)d_in[3];
  const float* rb1 = (const float*)d_in[4];
  const float* rW2 = (const float*)d_in[5];
  const float* rb2 = (const float*)d_in[6];
  const float* sW1 = (const float*)d_in[7];
  const float* sb1 = (const float*)d_in[8];
  const float* sW2 = (const float*)d_in[9];
  const float* sb2 = (const float*)d_in[10];
  const float* Wf  = (const float*)d_in[11];
  const float* bf  = (const float*)d_in[12];
  float* out = (float*)d_out;

  const int B = out_size / NSTEPS;        // 32768
  const int nblocks = B / ROWS;           // 1024 WGs -> 4 per CU (natural)
  hedger<<<nblocks, THREADS, 0, stream>>>(
      S, W0, b0, rW1, rb1, rW2, rb2, sW1, sb1, sW2, sb2, Wf, bf, out);
}

// Round 12
// 389.878 us; speedup vs baseline: 1.7257x; 1.0274x over previous
//
#include <hip/hip_runtime.h>
#include <math.h>

#define HID 128
#define NSTEPS 64
#define SLEN 65
#define THREADS 512   // R24: 8 waves/WG, M-split; 32 cols/wave kept
#define ROWS 64
#define ASTRIDE 136   // 128 + 8 f16 pad, 16B aligned rows
#define FSTRIDE 40    // 32 + 8 f16 pad
#define DSTR 68       // 64 + 4 f32 pad, 16B-aligned rows for b128 flush reads

typedef _Float16 half8 __attribute__((ext_vector_type(8)));
typedef __fp16 fp16x2 __attribute__((ext_vector_type(2)));
typedef float floatx4 __attribute__((ext_vector_type(4)));

// R24 = R21 4-phase structure with 8 waves/WG (512 thr), M-SPLIT:
// wave=(wavem,waven); each wave owns rows [wavem*32,+32) x cols
// [waven*32,+32). The only untried occupancy path that avoids ALL
// documented failure modes:
//  - cols/wave stays 32 -> LDS traffic law satisfied (per-CU A-bytes =
//    16 waves x 8KB = R21's 8 x 16KB = 128KB/GEMM). R16 failed by cutting
//    cols/wave; rows/wave is free. Conflicts must stay ~3.47e7 (law test).
//  - launch_bounds stays (,2) -> R22 allocator law respected (min-waves>2
//    collapses arch-VGPR target to 64 -> 2-3GB scratch; R15/R22).
//  - grid stays 512 = 2 WGs/CU (R21-proven resident; R23's 4-WG/CU via
//    smaller tiles never materialized and halved-tile overhead regressed).
// Waves/CU = 2 WG x 8 = 16 = 4/SIMD by construction. VGPR: R21 measured
// 120 w/ acc=32; acc halves to 16 -> est ~104 <= 128 (gate: CSV <= 128,
// else residency collapses to 1 WG/CU -> revert). LDS unchanged 73.8KB x2.
// Structure (R21): G2 deleted; v = lrelu(h0@sW1 + u@W25 + cvec); W25 =
// rW2@sW1 at init via 2 FULLY-UNROLLED GEMM passes (rule #20); delta =
// sigmoid(h0.Wf + u.wfu + v.ws2f + C) via 3 broadcast-B chains (waves 0-3).
// CLOSED: cols/wave != 32 (R3 spill; R16/R17 traffic law); min-waves>2
// (R15/R22); XOR swizzle (R14 structural); acc live across barriers (R18);
// runtime-indexed frag arrays (R20); <4 phases; smaller tiles (R23).
__global__ __launch_bounds__(THREADS, 2)
void hedger(const float* __restrict__ S,
            const float* __restrict__ W0,  const float* __restrict__ b0,
            const float* __restrict__ rW1, const float* __restrict__ rb1,
            const float* __restrict__ rW2, const float* __restrict__ rb2,
            const float* __restrict__ sW1, const float* __restrict__ sb1,
            const float* __restrict__ sW2, const float* __restrict__ sb2,
            const float* __restrict__ Wf,  const float* __restrict__ bfp,
            float* __restrict__ out)
{
  __shared__ __align__(16) _Float16 bufA[ROWS * ASTRIDE];   // h0   17408 B
  __shared__ __align__(16) _Float16 bufB[ROWS * ASTRIDE];   // u    17408 B
  __shared__ __align__(16) _Float16 bufC[ROWS * ASTRIDE];   // v    17408 B
  __shared__ __align__(16) _Float16 featb[ROWS * FSTRIDE];  //       5120 B
  __shared__ __align__(16) _Float16 WfS[HID];               //        256 B
  __shared__ __align__(16) _Float16 WfuS[HID];              // rW2@Wf 256 B
  __shared__ __align__(16) _Float16 Ws2S[HID];              // sW2@Wf 256 B
  __shared__             float    CvalS;
  __shared__ __align__(16) float    deltab[ROWS * DSTR];    //      17408 B
  // total ~73.8 KB -> 2 WGs/CU (147.6 <= 160 KB)

  const int tid  = threadIdx.x;
  const int wave = tid >> 6;            // 0..7
  const int lane = tid & 63;
  const int l15  = lane & 15;
  const int quad = lane >> 4;
  const int wavem = wave >> 2;          // 0..1  M-half
  const int waven = wave & 3;           // 0..3  N-slice
  const int mrow = wavem * 32;          // M-half base row
  const int r0 = blockIdx.x * ROWS;
  const int col0 = waven * 32 + 2 * l15; // lane's adjacent column pair

  // ---- persistent B fragments (96 VGPR): m=0 rW1, m=1 sW1, m=2 W25.
  half8 wfrag[3][4][2];  // [matrix][kIter][nt]
  {
    const float* Wm[2] = {rW1, sW1};
#pragma unroll
    for (int m = 0; m < 2; ++m)
#pragma unroll
      for (int kq = 0; kq < 4; ++kq)
#pragma unroll
        for (int nt = 0; nt < 2; ++nt) {
          const int n  = col0 + nt;
          const int kb = kq * 32 + quad * 8;
          half8 f;
#pragma unroll
          for (int j = 0; j < 8; ++j)
            f[j] = (_Float16)Wm[m][(kb + j) * HID + n];
          wfrag[m][kq][nt] = f;
        }
  }
  // W0 (8x128) zero-padded to K=32: only quad 0 (k<8) is real.
  half8 w0frag[2];
#pragma unroll
  for (int nt = 0; nt < 2; ++nt) {
    const int n = col0 + nt;
    half8 f;
#pragma unroll
    for (int j = 0; j < 8; ++j) {
      const int k = quad * 8 + j;
      f[j] = (k < 8) ? (_Float16)W0[k * HID + n] : (_Float16)0.f;
    }
    w0frag[nt] = f;
  }
  // biases: b0, rb1 direct; cvec = rb2@sW1 + sb1 via the lane's own sW1
  // fragments (quads partition k; shfl_xor 16/32 completes the dot).
  float b0r[2], rb1r[2], cv[2];
#pragma unroll
  for (int nt = 0; nt < 2; ++nt) {
    const int n = col0 + nt;
    b0r[nt] = b0[n]; rb1r[nt] = rb1[n];
    float p = 0.f;
#pragma unroll
    for (int kq = 0; kq < 4; ++kq) {
      const int kb = kq * 32 + quad * 8;
#pragma unroll
      for (int j = 0; j < 8; ++j)
        p += rb2[kb + j] * (float)wfrag[1][kq][nt][j];
    }
    p += __shfl_xor(p, 16);
    p += __shfl_xor(p, 32);
    cv[nt] = p + sb1[n];
  }

  // LDS init: featb zero-fill (pad cols 8..31 stay zero), Wf / wfu / ws2f
  // vectors, C scalar.
  for (int i = tid; i < ROWS * FSTRIDE; i += THREADS) featb[i] = (_Float16)0.f;
  if (tid < HID) {
    WfS[tid] = (_Float16)Wf[tid];
    float su = 0.f, ss = 0.f;
    for (int n = 0; n < HID; ++n) {
      su += rW2[tid * HID + n] * Wf[n];
      ss += sW2[tid * HID + n] * Wf[n];
    }
    WfuS[tid] = (_Float16)su;
    Ws2S[tid] = (_Float16)ss;
  }
  if (wave == 0) {   // C = (rb2 + sb2).Wf + bf
    float p = (rb2[lane] + sb2[lane]) * Wf[lane]
            + (rb2[lane + 64] + sb2[lane + 64]) * Wf[lane + 64];
    p += __shfl_xor(p, 1);  p += __shfl_xor(p, 2);  p += __shfl_xor(p, 4);
    p += __shfl_xor(p, 8);  p += __shfl_xor(p, 16); p += __shfl_xor(p, 32);
    if (lane == 0) CvalS = p + bfp[0];
  }

  // acc: 2x2 named floatx4 (16 VGPR), static indexing throughout.
  // ACC(MT,NT): MT = row-subtile within the wave's 32-row half.
  floatx4 acc00, acc01, acc10, acc11;
#define ACC(MT, NT) acc##MT##NT

#define INIT_BIAS(BR) do { \
  floatx4 z0 = {BR[0], BR[0], BR[0], BR[0]}; \
  floatx4 z1 = {BR[1], BR[1], BR[1], BR[1]}; \
  ACC(0,0) = z0; ACC(0,1) = z1; ACC(1,0) = z0; ACC(1,1) = z1; } while (0)

#define GEMM128(SRC, MI) do { \
  _Pragma("unroll") for (int kq = 0; kq < 4; ++kq) { \
    const half8 af0 = *(const half8*)&SRC[(mrow + l15) * ASTRIDE + kq * 32 + quad * 8]; \
    const half8 af1 = *(const half8*)&SRC[(mrow + 16 + l15) * ASTRIDE + kq * 32 + quad * 8]; \
    ACC(0,0) = __builtin_amdgcn_mfma_f32_16x16x32_f16(af0, wfrag[MI][kq][0], ACC(0,0), 0, 0, 0); \
    ACC(0,1) = __builtin_amdgcn_mfma_f32_16x16x32_f16(af0, wfrag[MI][kq][1], ACC(0,1), 0, 0, 0); \
    ACC(1,0) = __builtin_amdgcn_mfma_f32_16x16x32_f16(af1, wfrag[MI][kq][0], ACC(1,0), 0, 0, 0); \
    ACC(1,1) = __builtin_amdgcn_mfma_f32_16x16x32_f16(af1, wfrag[MI][kq][1], ACC(1,1), 0, 0, 0); \
  } } while (0)

#define EPI_LRELU_MT(DST, MT) do { \
  _Pragma("unroll") for (int r = 0; r < 4; ++r) { \
    const int row = mrow + MT * 16 + quad * 4 + r; \
    const float v0 = ACC(MT,0)[r]; \
    const float v1 = ACC(MT,1)[r]; \
    fp16x2 h2 = {(__fp16)fmaxf(v0, 0.2f * v0), (__fp16)fmaxf(v1, 0.2f * v1)}; \
    *(fp16x2*)&DST[row * ASTRIDE + col0] = h2; \
  } } while (0)
#define EPI_LRELU(DST) do { EPI_LRELU_MT(DST, 0); EPI_LRELU_MT(DST, 1); } while (0)

#define EPI_STORE_MT(DST, MT) do { \
  _Pragma("unroll") for (int r = 0; r < 4; ++r) { \
    const int row = mrow + MT * 16 + quad * 4 + r; \
    fp16x2 h2 = {(__fp16)ACC(MT,0)[r], (__fp16)ACC(MT,1)[r]}; \
    *(fp16x2*)&DST[row * ASTRIDE + col0] = h2; \
  } } while (0)
#define EPI_STORE(DST) do { EPI_STORE_MT(DST, 0); EPI_STORE_MT(DST, 1); } while (0)

  // ---- init-time W25 = rW2 @ sW1: 2 FULLY-UNROLLED GEMM passes (rule #20:
  // every wfrag[2][kq] index compile-time). Pass h stages rW2 rows
  // [64h,64h+64) into bufA, GEMMs vs sW1 frags, EPI to bufB, gathers this
  // half's two B-fragments (kq = 2h+kqh; kl = kqh*32+quad*8+j).
#pragma unroll
  for (int h = 0; h < 2; ++h) {
    __syncthreads();                       // bufA/bufB free (covers featb fill)
    for (int i = tid; i < ROWS * HID; i += THREADS) {
      const int row = i >> 7, c = i & 127;
      bufA[row * ASTRIDE + c] = (_Float16)rW2[(h * 64 + row) * HID + c];
    }
    __syncthreads();
    {
      float zr[2] = {0.f, 0.f};
      INIT_BIAS(zr);
      GEMM128(bufA, 1);
      EPI_STORE(bufB);
    }
    __syncthreads();
#pragma unroll
    for (int kqh = 0; kqh < 2; ++kqh) {
      const int kq = h * 2 + kqh;          // compile-time
      half8 f0, f1;
#pragma unroll
      for (int j = 0; j < 8; ++j) {
        const int kl = kqh * 32 + quad * 8 + j;   // 0..63 within this half
        const fp16x2 pr = *(const fp16x2*)&bufB[kl * ASTRIDE + col0];
        f0[j] = (_Float16)pr[0];
        f1[j] = (_Float16)pr[1];
      }
      wfrag[2][kq][0] = f0;
      wfrag[2][kq][1] = f1;
    }
  }
  __syncthreads();   // gathers done; bufA/bufB return to loop use

  // step-0 features (threads 0..63 = wave 0, one row each; S from global)
  float lm_prev = 0.f, cum_x = 0.f, qv = 0.f;
  const float* Srow = S + (size_t)(r0 + (tid & (ROWS - 1))) * SLEN;
  if (tid < ROWS) {
    const float lm = logf(Srow[0] * 0.01f);
    lm_prev = lm; cum_x = lm; qv = 0.f;
    _Float16* fr = &featb[tid * FSTRIDE];
    fr[0] = (_Float16)lm;
    fr[1] = (_Float16)1.0f;
    fr[2] = (_Float16)0.235f;
    fr[3] = (_Float16)0.f;                 // delta_0 = 0
    fr[4] = (_Float16)lm;                  // run_mean at k=0
    fr[5] = (_Float16)0.f;
    fr[6] = (_Float16)(1.9f * sqrtf(1e-12f));
    fr[7] = (_Float16)0.f;
  }
  __syncthreads();
  const float Cval = CvalS;

#pragma unroll 1
  for (int k = 0; k < NSTEPS; ++k) {
    // G0: h0 = lrelu(featPad @ W0pad + b0)
    INIT_BIAS(b0r);
    {
      const half8 af0 = *(const half8*)&featb[(mrow + l15) * FSTRIDE + quad * 8];
      const half8 af1 = *(const half8*)&featb[(mrow + 16 + l15) * FSTRIDE + quad * 8];
      ACC(0,0) = __builtin_amdgcn_mfma_f32_16x16x32_f16(af0, w0frag[0], ACC(0,0), 0, 0, 0);
      ACC(0,1) = __builtin_amdgcn_mfma_f32_16x16x32_f16(af0, w0frag[1], ACC(0,1), 0, 0, 0);
      ACC(1,0) = __builtin_amdgcn_mfma_f32_16x16x32_f16(af1, w0frag[0], ACC(1,0), 0, 0, 0);
      ACC(1,1) = __builtin_amdgcn_mfma_f32_16x16x32_f16(af1, w0frag[1], ACC(1,1), 0, 0, 0);
    }
    EPI_LRELU(bufA);
    __syncthreads();                                   // bar A: h0 in bufA

    // delta-independent features of step k+1 — overlaps G1.
    // (Srow[k+1] valid at k=63: SLEN=65; write is dead then, harmless.)
    if (tid < ROWS) {
      const int kk = k + 1;
      const float lm = logf(Srow[kk] * 0.01f);
      const float rr = lm - lm_prev; qv += rr * rr;
      lm_prev = lm; cum_x += lm;
      const float tT = (float)kk * (1.f / 64.f);
      _Float16* fr = &featb[tid * FSTRIDE];
      fr[0] = (_Float16)lm;
      fr[1] = (_Float16)(1.f - tT);
      fr[4] = (_Float16)(cum_x / (float)(kk + 1));
      fr[5] = (_Float16)qv;
      fr[6] = (_Float16)(1.9f * sqrtf(qv + 1e-12f));
      fr[7] = (_Float16)tT;
    }

    // G1: u = lrelu(h0 @ rW1 + rb1)
    INIT_BIAS(rb1r);  GEMM128(bufA, 0);  EPI_LRELU(bufB);
    __syncthreads();                                   // bar B: u in bufB

    // G23: v = lrelu(h0 @ sW1 + u @ W25 + cvec)   (G2 deleted)
    INIT_BIAS(cv);
    GEMM128(bufA, 1);
    GEMM128(bufB, 2);
    EPI_LRELU(bufC);
    __syncthreads();                                   // bar C: v in bufC

    // WF: delta = sigmoid(h0.Wf + u.wfu + v.ws2f + C); waves 0-3 cover the
    // 64 rows via three independent broadcast-B MFMA chains; waves 4-7 idle.
    if (wave < 4) {
      floatx4 d1 = {0.f, 0.f, 0.f, 0.f};
      floatx4 d2 = {0.f, 0.f, 0.f, 0.f};
      floatx4 d3 = {0.f, 0.f, 0.f, 0.f};
      const int arow = (wave * 16 + l15) * ASTRIDE;
#pragma unroll
      for (int kq = 0; kq < 4; ++kq) {
        const int off = kq * 32 + quad * 8;
        const half8 a1 = *(const half8*)&bufA[arow + off];
        const half8 w1 = *(const half8*)&WfS[off];
        d1 = __builtin_amdgcn_mfma_f32_16x16x32_f16(a1, w1, d1, 0, 0, 0);
        const half8 a2 = *(const half8*)&bufB[arow + off];
        const half8 w2 = *(const half8*)&WfuS[off];
        d2 = __builtin_amdgcn_mfma_f32_16x16x32_f16(a2, w2, d2, 0, 0, 0);
        const half8 a3 = *(const half8*)&bufC[arow + off];
        const half8 w3 = *(const half8*)&Ws2S[off];
        d3 = __builtin_amdgcn_mfma_f32_16x16x32_f16(a3, w3, d3, 0, 0, 0);
      }
      if (l15 < 4) {
        // static-index select (rule: no runtime vector index)
        const float s1 = (l15 & 2) ? ((l15 & 1) ? d1[3] : d1[2])
                                   : ((l15 & 1) ? d1[1] : d1[0]);
        const float s2 = (l15 & 2) ? ((l15 & 1) ? d2[3] : d2[2])
                                   : ((l15 & 1) ? d2[1] : d2[0]);
        const float s3 = (l15 & 2) ? ((l15 & 1) ? d3[3] : d3[2])
                                   : ((l15 & 1) ? d3[1] : d3[0]);
        const int row = wave * 16 + quad * 4 + l15;
        const float d = 1.f / (1.f + expf(-(s1 + s2 + s3 + Cval)));
        featb[row * FSTRIDE + 3] = (_Float16)d;        // fr[3] for step k+1
        deltab[row * DSTR + k] = d;                    // staged output
      }
    }
    __syncthreads();                                   // bar D: featb complete
  }

  // coalesced output flush: 64 rows x 64 steps; 512 threads, 2 dwordx4 each.
  {
    const int row = tid >> 3;                // 0..63
    const int c0  = (tid & 7) * 8;           // 0,8,...,56
    const float* dr = &deltab[row * DSTR + c0];
    float* orow = &out[(size_t)(r0 + row) * NSTEPS + c0];
#pragma unroll
    for (int u = 0; u < 2; ++u) {
      const floatx4 v = *(const floatx4*)&dr[u * 4];
      *(floatx4*)&orow[u * 4] = v;
    }
  }
#undef INIT_BIAS
#undef GEMM128
#undef EPI_LRELU
#undef EPI_LRELU_MT
#undef EPI_STORE
#undef EPI_STORE_MT
#undef ACC
}

extern "C" void kernel_launch(void* const* d_in, const int* in_sizes, int n_in,
                              void* d_out, int out_size, void* d_ws, size_t ws_size,
                              hipStream_t stream) {
  const float* S   = (const float*)d_in[0];
  const float* W0  = (const float*)d_in[1];
  const float* b0  = (const float*)d_in[2];
  const float* rW1 = (const float*)d_in[3];
  const float* rb1 = (const float*)d_in[4];
  const float* rW2 = (const float*)d_in[5];
  const float* rb2 = (const float*)d_in[6];
  const float* sW1 = (const float*)d_in[7];
  const float* sb1 = (const float*)d_in[8];
  const float* sW2 = (const float*)d_in[9];
  const float* sb2 = (const float*)d_in[10];
  const float* Wf  = (const float*)d_in[11];
  const float* bf  = (const float*)d_in[12];
  float* out = (float*)d_out;

  const int B = out_size / NSTEPS;        // 32768
  const int nblocks = B / ROWS;           // 512 WGs -> 2 per CU
  hedger<<<nblocks, THREADS, 0, stream>>>(
      S, W0, b0, rW1, rb1, rW2, rb2, sW1, sb1, sW2, sb2, Wf, bf, out);
}

// Round 14
// 348.636 us; speedup vs baseline: 1.9298x; 1.1183x over previous
//
#include <hip/hip_runtime.h>
#include <math.h>

#define HID 128
#define NSTEPS 64
#define SLEN 65
#define THREADS 256
#define ROWS 64
#define ASTRIDE 136   // 128 + 8 f16 pad, 16B aligned rows
#define FSTRIDE 40    // 32 + 8 f16 pad
#define DSTR 68       // 64 + 4 f32 pad, 16B-aligned rows for b128 flush reads

typedef _Float16 half8 __attribute__((ext_vector_type(8)));
typedef __fp16 fp16x2 __attribute__((ext_vector_type(2)));
typedef float floatx4 __attribute__((ext_vector_type(4)));

// R26 = R25 resubmit (R13 infra failure: "container failed twice", no
// counters -> theory untested, not falsified; re-run the same experiment).
// R25 = R21 (309us, best) + two scheduling micro-levers; geometry frozen.
// OCCUPANCY ARM CLOSED (R15/R16/R17/R22/R23/R24): kernel pins at ~8
// waves/CU (2/SIMD) under every legal geometry; all reshapes lose. R24
// confirmed the traffic law (rows/wave split: conflicts 3.44e7 ~ R21) but
// occupancy stayed 23% and dur 367 > 309.
// R25 CHANGES:
//  (1) T5 s_setprio(1)/(0) around every MFMA cluster: 2 independent WGs/CU
//      at different phases = the regime where setprio pays (m191 +4-7%),
//      not the lockstep-null case (m190). SALU-only, zero reg impact.
//  (2) Feature-straggler balance: per-step logf/sqrt chain was wave-0-only
//      (64 thr) -> waves 1-3 waited at bar B every step. Now 16 rows/wave
//      (lane<16, row=wave*16+l15); recurrence state stays thread-local.
// Structure (R21): 4 phases/barriers. G2 deleted: v = lrelu(h0@sW1 + u@W25
// + cvec), W25 = rW2@sW1 at init via 2 FULLY-UNROLLED GEMM passes (rule
// #20); delta = sigmoid(h0.Wf + u.wfu + v.ws2f + C), 3 broadcast-B chains.
// Gates: VGPR<=128-ish (~120), FETCH ~5.3MB, WRITE == out 8.19MB.
// CLOSED: cols/wave != 32 (R3; traffic law bytes ~ 128/colsPerWave);
// min-waves>2 bounds (R15/R22: allocator target collapses to 64);
// XOR swizzle (R14: conflicts structural b128 serialization); acc live
// across barriers (R18 spill); runtime-indexed frag arrays (R20 rule #20);
// <4 phases (nonlinear chain); any tile/wave reshape (R23/R24).
__global__ __launch_bounds__(THREADS, 2)
void hedger(const float* __restrict__ S,
            const float* __restrict__ W0,  const float* __restrict__ b0,
            const float* __restrict__ rW1, const float* __restrict__ rb1,
            const float* __restrict__ rW2, const float* __restrict__ rb2,
            const float* __restrict__ sW1, const float* __restrict__ sb1,
            const float* __restrict__ sW2, const float* __restrict__ sb2,
            const float* __restrict__ Wf,  const float* __restrict__ bfp,
            float* __restrict__ out)
{
  __shared__ __align__(16) _Float16 bufA[ROWS * ASTRIDE];   // h0   17408 B
  __shared__ __align__(16) _Float16 bufB[ROWS * ASTRIDE];   // u    17408 B
  __shared__ __align__(16) _Float16 bufC[ROWS * ASTRIDE];   // v    17408 B
  __shared__ __align__(16) _Float16 featb[ROWS * FSTRIDE];  //       5120 B
  __shared__ __align__(16) _Float16 WfS[HID];               //        256 B
  __shared__ __align__(16) _Float16 WfuS[HID];              // rW2@Wf 256 B
  __shared__ __align__(16) _Float16 Ws2S[HID];              // sW2@Wf 256 B
  __shared__             float    CvalS;
  __shared__ __align__(16) float    deltab[ROWS * DSTR];    //      17408 B
  // total ~75.5 KB -> 2 WGs/CU

  const int tid  = threadIdx.x;
  const int wave = tid >> 6;            // 0..3
  const int lane = tid & 63;
  const int l15  = lane & 15;
  const int quad = lane >> 4;
  const int n_base = wave * 32;
  const int r0 = blockIdx.x * ROWS;
  const int col0 = n_base + 2 * l15;    // lane's adjacent column pair

  // ---- persistent B fragments (96 VGPR): m=0 rW1, m=1 sW1, m=2 W25.
  half8 wfrag[3][4][2];  // [matrix][kIter][nt]
  {
    const float* Wm[2] = {rW1, sW1};
#pragma unroll
    for (int m = 0; m < 2; ++m)
#pragma unroll
      for (int kq = 0; kq < 4; ++kq)
#pragma unroll
        for (int nt = 0; nt < 2; ++nt) {
          const int n  = col0 + nt;
          const int kb = kq * 32 + quad * 8;
          half8 f;
#pragma unroll
          for (int j = 0; j < 8; ++j)
            f[j] = (_Float16)Wm[m][(kb + j) * HID + n];
          wfrag[m][kq][nt] = f;
        }
  }
  // W0 (8x128) zero-padded to K=32: only quad 0 (k<8) is real.
  half8 w0frag[2];
#pragma unroll
  for (int nt = 0; nt < 2; ++nt) {
    const int n = col0 + nt;
    half8 f;
#pragma unroll
    for (int j = 0; j < 8; ++j) {
      const int k = quad * 8 + j;
      f[j] = (k < 8) ? (_Float16)W0[k * HID + n] : (_Float16)0.f;
    }
    w0frag[nt] = f;
  }
  // biases: b0, rb1 direct; cvec = rb2@sW1 + sb1 via the lane's own sW1
  // fragments (quads partition k; shfl_xor 16/32 completes the dot).
  float b0r[2], rb1r[2], cv[2];
#pragma unroll
  for (int nt = 0; nt < 2; ++nt) {
    const int n = col0 + nt;
    b0r[nt] = b0[n]; rb1r[nt] = rb1[n];
    float p = 0.f;
#pragma unroll
    for (int kq = 0; kq < 4; ++kq) {
      const int kb = kq * 32 + quad * 8;
#pragma unroll
      for (int j = 0; j < 8; ++j)
        p += rb2[kb + j] * (float)wfrag[1][kq][nt][j];
    }
    p += __shfl_xor(p, 16);
    p += __shfl_xor(p, 32);
    cv[nt] = p + sb1[n];
  }

  // LDS init: featb zero-fill (pad cols 8..31 stay zero), Wf / wfu / ws2f
  // vectors, C scalar.
  for (int i = tid; i < ROWS * FSTRIDE; i += THREADS) featb[i] = (_Float16)0.f;
  if (tid < HID) {
    WfS[tid] = (_Float16)Wf[tid];
    float su = 0.f, ss = 0.f;
    for (int n = 0; n < HID; ++n) {
      su += rW2[tid * HID + n] * Wf[n];
      ss += sW2[tid * HID + n] * Wf[n];
    }
    WfuS[tid] = (_Float16)su;
    Ws2S[tid] = (_Float16)ss;
  }
  if (wave == 0) {   // C = (rb2 + sb2).Wf + bf
    float p = (rb2[lane] + sb2[lane]) * Wf[lane]
            + (rb2[lane + 64] + sb2[lane + 64]) * Wf[lane + 64];
    p += __shfl_xor(p, 1);  p += __shfl_xor(p, 2);  p += __shfl_xor(p, 4);
    p += __shfl_xor(p, 8);  p += __shfl_xor(p, 16); p += __shfl_xor(p, 32);
    if (lane == 0) CvalS = p + bfp[0];
  }

  floatx4 acc[4][2];

#define INIT_BIAS(BR) do { \
  _Pragma("unroll") for (int mt = 0; mt < 4; ++mt) \
  _Pragma("unroll") for (int nt = 0; nt < 2; ++nt) { \
    floatx4 z = {BR[nt], BR[nt], BR[nt], BR[nt]}; acc[mt][nt] = z; } } while (0)

#define GEMM128(SRC, MI) do { \
  __builtin_amdgcn_s_setprio(1); \
  _Pragma("unroll") for (int kq = 0; kq < 4; ++kq) { \
    half8 afr[4]; \
    _Pragma("unroll") for (int mt = 0; mt < 4; ++mt) \
      afr[mt] = *(const half8*)&SRC[(mt * 16 + l15) * ASTRIDE + kq * 32 + quad * 8]; \
    _Pragma("unroll") for (int mt = 0; mt < 4; ++mt) \
    _Pragma("unroll") for (int nt = 0; nt < 2; ++nt) \
      acc[mt][nt] = __builtin_amdgcn_mfma_f32_16x16x32_f16( \
          afr[mt], wfrag[MI][kq][nt], acc[mt][nt], 0, 0, 0); \
  } \
  __builtin_amdgcn_s_setprio(0); } while (0)

#define EPI_LRELU(DST) do { \
  _Pragma("unroll") for (int mt = 0; mt < 4; ++mt) \
  _Pragma("unroll") for (int r = 0; r < 4; ++r) { \
    const int row = mt * 16 + quad * 4 + r; \
    const float v0 = acc[mt][0][r]; \
    const float v1 = acc[mt][1][r]; \
    fp16x2 h2 = {(__fp16)fmaxf(v0, 0.2f * v0), (__fp16)fmaxf(v1, 0.2f * v1)}; \
    *(fp16x2*)&DST[row * ASTRIDE + col0] = h2; \
  } } while (0)

#define EPI_STORE(DST) do { \
  _Pragma("unroll") for (int mt = 0; mt < 4; ++mt) \
  _Pragma("unroll") for (int r = 0; r < 4; ++r) { \
    const int row = mt * 16 + quad * 4 + r; \
    fp16x2 h2 = {(__fp16)acc[mt][0][r], (__fp16)acc[mt][1][r]}; \
    *(fp16x2*)&DST[row * ASTRIDE + col0] = h2; \
  } } while (0)

  // ---- init-time W25 = rW2 @ sW1 via the GEMM machinery (2 half passes).
  // FULLY UNROLLED over h (rule #20): every wfrag[2][kq][nt] index below is
  // a compile-time constant, keeping wfrag in VGPRs.
#pragma unroll
  for (int h = 0; h < 2; ++h) {
    __syncthreads();                       // bufA/bufB free (also covers featb fill)
    for (int i = tid; i < ROWS * HID; i += THREADS) {
      const int row = i >> 7, c = i & 127;
      bufA[row * ASTRIDE + c] = (_Float16)rW2[(h * 64 + row) * HID + c];
    }
    __syncthreads();
    {
      float zr[2] = {0.f, 0.f};
      INIT_BIAS(zr);
      GEMM128(bufA, 1);
      EPI_STORE(bufB);
    }
    __syncthreads();
#pragma unroll
    for (int kqh = 0; kqh < 2; ++kqh) {
      const int kq = h * 2 + kqh;          // compile-time (h, kqh unrolled)
      half8 f0, f1;
#pragma unroll
      for (int j = 0; j < 8; ++j) {
        const int kl = kq * 32 + quad * 8 + j - h * 64;   // 0..63
        const fp16x2 p = *(const fp16x2*)&bufB[kl * ASTRIDE + col0];
        f0[j] = (_Float16)p[0];
        f1[j] = (_Float16)p[1];
      }
      wfrag[2][kq][0] = f0;
      wfrag[2][kq][1] = f1;
    }
  }
  __syncthreads();   // gathers done; bufA/bufB return to loop use

  // step-0 features. R25: 16 rows/wave (lane<16) -> no wave-0 straggler.
  // Row<->thread map fixed across steps; recurrence state thread-local.
  const int frow = wave * 16 + l15;        // 0..63 (valid for all threads)
  float lm_prev = 0.f, cum_x = 0.f, qv = 0.f;
  const float* Srow = S + (size_t)(r0 + frow) * SLEN;
  if (lane < 16) {
    const float lm = logf(Srow[0] * 0.01f);
    lm_prev = lm; cum_x = lm; qv = 0.f;
    _Float16* fr = &featb[frow * FSTRIDE];
    fr[0] = (_Float16)lm;
    fr[1] = (_Float16)1.0f;
    fr[2] = (_Float16)0.235f;
    fr[3] = (_Float16)0.f;                 // delta_0 = 0
    fr[4] = (_Float16)lm;                  // run_mean at k=0
    fr[5] = (_Float16)0.f;
    fr[6] = (_Float16)(1.9f * sqrtf(1e-12f));
    fr[7] = (_Float16)0.f;
  }
  __syncthreads();
  const float Cval = CvalS;

#pragma unroll 1
  for (int k = 0; k < NSTEPS; ++k) {
    // G0: h0 = lrelu(featPad @ W0pad + b0)
    INIT_BIAS(b0r);
    {
      half8 afr[4];
#pragma unroll
      for (int mt = 0; mt < 4; ++mt)
        afr[mt] = *(const half8*)&featb[(mt * 16 + l15) * FSTRIDE + quad * 8];
      __builtin_amdgcn_s_setprio(1);
#pragma unroll
      for (int mt = 0; mt < 4; ++mt)
#pragma unroll
        for (int nt = 0; nt < 2; ++nt)
          acc[mt][nt] = __builtin_amdgcn_mfma_f32_16x16x32_f16(
              afr[mt], w0frag[nt], acc[mt][nt], 0, 0, 0);
      __builtin_amdgcn_s_setprio(0);
    }
    EPI_LRELU(bufA);
    __syncthreads();                                   // bar A: h0 in bufA

    // delta-independent features of step k+1 — 16 rows/wave, overlaps G1.
    // (Srow[k+1] valid at k=63: SLEN=65; write is dead then, harmless.)
    if (lane < 16) {
      const int kk = k + 1;
      const float lm = logf(Srow[kk] * 0.01f);
      const float rr = lm - lm_prev; qv += rr * rr;
      lm_prev = lm; cum_x += lm;
      const float tT = (float)kk * (1.f / 64.f);
      _Float16* fr = &featb[frow * FSTRIDE];
      fr[0] = (_Float16)lm;
      fr[1] = (_Float16)(1.f - tT);
      fr[4] = (_Float16)(cum_x / (float)(kk + 1));
      fr[5] = (_Float16)qv;
      fr[6] = (_Float16)(1.9f * sqrtf(qv + 1e-12f));
      fr[7] = (_Float16)tT;
    }

    // G1: u = lrelu(h0 @ rW1 + rb1)
    INIT_BIAS(rb1r);  GEMM128(bufA, 0);  EPI_LRELU(bufB);
    __syncthreads();                                   // bar B: u in bufB

    // G23: v = lrelu(h0 @ sW1 + u @ W25 + cvec)   (G2 deleted)
    INIT_BIAS(cv);
    GEMM128(bufA, 1);
    GEMM128(bufB, 2);
    EPI_LRELU(bufC);
    __syncthreads();                                   // bar C: v in bufC

    // WF: delta = sigmoid(h0.Wf + u.wfu + v.ws2f + C), three independent
    // broadcast-B MFMA chains; no cross-barrier register liveness.
    {
      floatx4 d1 = {0.f, 0.f, 0.f, 0.f};
      floatx4 d2 = {0.f, 0.f, 0.f, 0.f};
      floatx4 d3 = {0.f, 0.f, 0.f, 0.f};
      const int arow = (wave * 16 + l15) * ASTRIDE;
      __builtin_amdgcn_s_setprio(1);
#pragma unroll
      for (int kq = 0; kq < 4; ++kq) {
        const int off = kq * 32 + quad * 8;
        const half8 a1 = *(const half8*)&bufA[arow + off];
        const half8 w1 = *(const half8*)&WfS[off];
        d1 = __builtin_amdgcn_mfma_f32_16x16x32_f16(a1, w1, d1, 0, 0, 0);
        const half8 a2 = *(const half8*)&bufB[arow + off];
        const half8 w2 = *(const half8*)&WfuS[off];
        d2 = __builtin_amdgcn_mfma_f32_16x16x32_f16(a2, w2, d2, 0, 0, 0);
        const half8 a3 = *(const half8*)&bufC[arow + off];
        const half8 w3 = *(const half8*)&Ws2S[off];
        d3 = __builtin_amdgcn_mfma_f32_16x16x32_f16(a3, w3, d3, 0, 0, 0);
      }
      __builtin_amdgcn_s_setprio(0);
      if (l15 < 4) {
        // static-index select (rule: no runtime vector index)
        const float s1 = (l15 & 2) ? ((l15 & 1) ? d1[3] : d1[2])
                                   : ((l15 & 1) ? d1[1] : d1[0]);
        const float s2 = (l15 & 2) ? ((l15 & 1) ? d2[3] : d2[2])
                                   : ((l15 & 1) ? d2[1] : d2[0]);
        const float s3 = (l15 & 2) ? ((l15 & 1) ? d3[3] : d3[2])
                                   : ((l15 & 1) ? d3[1] : d3[0]);
        const int row = wave * 16 + quad * 4 + l15;
        const float d = 1.f / (1.f + expf(-(s1 + s2 + s3 + Cval)));
        featb[row * FSTRIDE + 3] = (_Float16)d;        // fr[3] for step k+1
        deltab[row * DSTR + k] = d;                    // staged output
      }
    }
    __syncthreads();                                   // bar D: featb complete
  }

  // coalesced output flush: 64 rows x 64 steps, dwordx4 stores.
  {
    const int row = tid >> 2;                // 0..63
    const int c0  = (tid & 3) * 16;          // 0,16,32,48
    const float* dr = &deltab[row * DSTR + c0];
    float* orow = &out[(size_t)(r0 + row) * NSTEPS + c0];
#pragma unroll
    for (int u = 0; u < 4; ++u) {
      const floatx4 v = *(const floatx4*)&dr[u * 4];
      *(floatx4*)&orow[u * 4] = v;
    }
  }
#undef INIT_BIAS
#undef GEMM128
#undef EPI_LRELU
#undef EPI_STORE
}

extern "C" void kernel_launch(void* const* d_in, const int* in_sizes, int n_in,
                              void* d_out, int out_size, void* d_ws, size_t ws_size,
                              hipStream_t stream) {
  const float* S   = (const float*)d_in[0];
  const float* W0  = (const float*)d_in[1];
  const float* b0  = (const float*)d_in[2];
  const float* rW1 = (const float*)d_in[3];
  const float* rb1 = (const float*)d_in[4];
  const float* rW2 = (const float*)d_in[5];
  const float* rb2 = (const float*)d_in[6];
  const float* sW1 = (const float*)d_in[7];
  const float* sb1 = (const float*)d_in[8];
  const float* sW2 = (const float*)d_in[9];
  const float* sb2 = (const float*)d_in[10];
  const float* Wf  = (const float*)d_in[11];
  const float* bf  = (const float*)d_in[12];
  float* out = (float*)d_out;

  const int B = out_size / NSTEPS;        // 32768
  const int nblocks = B / ROWS;           // 512 WGs -> 2 per CU
  hedger<<<nblocks, THREADS, 0, stream>>>(
      S, W0, b0, rW1, rb1, rW2, rb2, sW1, sb1, sW2, sb2, Wf, bf, out);
}